// Round 1
// baseline (740.114 us; speedup 1.0000x reference)
//
#include <hip/hip_runtime.h>
#include <hip/hip_bf16.h>

// GCN 2-layer inference, N=100000 nodes, E=1600000 edges, F_IN=100, H=128, C=47.
// Strategy: build CSR by dst per call (deg count -> scan -> scatter), then
//   gemm1 (x@W1, fp32, W1 in LDS) -> agg1 (gather+relu+bias) ->
//   gemm2 (h@W2, fp32, W2 in LDS) -> agg2 (gather+bias -> out).
// All gathers are per-node (one wave per node) -> no float atomics, deterministic-ish.

constexpr int N    = 100000;
constexpr int E    = 1600000;
constexpr int FIN  = 100;
constexpr int HD   = 128;
constexpr int C    = 47;
constexpr int EN   = E + N;          // edges + self loops
constexpr int SCAN_CHUNK = 2048;     // 256 threads * 8
constexpr int NB_SCAN = (N + SCAN_CHUNK - 1) / SCAN_CHUNK;  // 49

// ---------- CSR build ----------

__global__ void init_cnt(int* __restrict__ cnt) {
    int i = blockIdx.x * 256 + threadIdx.x;
    if (i < N) cnt[i] = 1;   // self loop contributes 1 to each node's in-degree
}

__global__ void count_deg(const int* __restrict__ dst, int* __restrict__ cnt) {
    int e = blockIdx.x * 256 + threadIdx.x;
    if (e < E) atomicAdd(&cnt[dst[e]], 1);
}

__global__ void scan_pass1(const int* __restrict__ cnt, int* __restrict__ partials) {
    int t = threadIdx.x, b = blockIdx.x;
    int base = b * SCAN_CHUNK + t * 8;
    int s = 0;
#pragma unroll
    for (int i = 0; i < 8; ++i) {
        int idx = base + i;
        if (idx < N) s += cnt[idx];
    }
    __shared__ int sm[256];
    sm[t] = s;
    __syncthreads();
    for (int off = 128; off > 0; off >>= 1) {
        if (t < off) sm[t] += sm[t + off];
        __syncthreads();
    }
    if (t == 0) partials[b] = sm[0];
}

__global__ void scan_pass2(const int* __restrict__ partials, int* __restrict__ pscan,
                           int* __restrict__ rowptr) {
    if (threadIdx.x == 0) {
        int run = 0;
        for (int i = 0; i < NB_SCAN; ++i) { pscan[i] = run; run += partials[i]; }
        rowptr[N] = run;   // == E + N
    }
}

__global__ void scan_pass3(const int* __restrict__ cnt, const int* __restrict__ pscan,
                           int* __restrict__ rowptr) {
    int t = threadIdx.x, b = blockIdx.x;
    int base = b * SCAN_CHUNK + t * 8;
    int v[8];
    int s = 0;
#pragma unroll
    for (int i = 0; i < 8; ++i) {
        int idx = base + i;
        v[i] = (idx < N) ? cnt[idx] : 0;
        s += v[i];
    }
    __shared__ int sm[256];
    sm[t] = s;
    __syncthreads();
    // Hillis-Steele inclusive scan over 256 thread sums
    for (int off = 1; off < 256; off <<= 1) {
        int tv = (t >= off) ? sm[t - off] : 0;
        __syncthreads();
        sm[t] += tv;
        __syncthreads();
    }
    int excl = sm[t] - s + pscan[b];
#pragma unroll
    for (int i = 0; i < 8; ++i) {
        int idx = base + i;
        if (idx < N) { rowptr[idx] = excl; excl += v[i]; }
    }
}

__global__ void dinv_fill(const int* __restrict__ cnt, float* __restrict__ dinv,
                          int* __restrict__ fill) {
    int i = blockIdx.x * 256 + threadIdx.x;
    if (i < N) {
        dinv[i] = rsqrtf((float)cnt[i]);   // deg >= 1 always (self loop)
        fill[i] = 0;
    }
}

__global__ void scatter_edges(const int* __restrict__ ei, const int* __restrict__ rowptr,
                              int* __restrict__ fill, const float* __restrict__ dinv,
                              int* __restrict__ esrc, float* __restrict__ enorm) {
    int e = blockIdx.x * 256 + threadIdx.x;
    if (e < E) {
        int s = ei[e];
        int d = ei[E + e];
        int pos = rowptr[d] + atomicAdd(&fill[d], 1);
        esrc[pos] = s;
        enorm[pos] = dinv[s] * dinv[d];
    } else if (e < EN) {
        int i = e - E;
        int pos = rowptr[i] + atomicAdd(&fill[i], 1);
        esrc[pos] = i;
        enorm[pos] = dinv[i] * dinv[i];
    }
}

// ---------- GEMM1: xw[N,128] = x[N,100] @ W1[100,128] ----------
// 64 nodes per block; W1 (51.2KB) + x-tile (25.6KB) in LDS.

__global__ __launch_bounds__(256) void gemm1(const float* __restrict__ x,
                                             const float* __restrict__ W1,
                                             float* __restrict__ xw) {
    __shared__ float sW[FIN * HD];     // 12800 floats
    __shared__ float sX[64 * FIN];     // 6400 floats
    int tx = threadIdx.x;
    size_t node0 = (size_t)blockIdx.x * 64;

    for (int i = tx; i < FIN * HD; i += 256) sW[i] = W1[i];
    size_t base = node0 * FIN;
    for (int i = tx; i < 64 * FIN; i += 256) {
        size_t g = base + i;
        sX[i] = (g < (size_t)N * FIN) ? x[g] : 0.f;
    }
    __syncthreads();

    int col = (tx & 31) * 4;        // 0..124
    int nb  = (tx >> 5) * 8;        // 0..56
    float4 acc[8];
#pragma unroll
    for (int i = 0; i < 8; ++i) acc[i] = make_float4(0.f, 0.f, 0.f, 0.f);

    for (int k = 0; k < FIN; ++k) {
        float4 b = *(const float4*)&sW[k * HD + col];
#pragma unroll
        for (int i = 0; i < 8; ++i) {
            float a = sX[(nb + i) * FIN + k];
            acc[i].x = fmaf(a, b.x, acc[i].x);
            acc[i].y = fmaf(a, b.y, acc[i].y);
            acc[i].z = fmaf(a, b.z, acc[i].z);
            acc[i].w = fmaf(a, b.w, acc[i].w);
        }
    }
#pragma unroll
    for (int i = 0; i < 8; ++i) {
        size_t node = node0 + nb + i;
        if (node < (size_t)N) *(float4*)&xw[node * HD + col] = acc[i];
    }
}

// ---------- agg1: h[n] = relu(b1 + sum_j norm_j * xw[src_j]) ----------
// one wave per node, float2 per lane (128 features)

__global__ __launch_bounds__(256) void agg1(const float* __restrict__ xw,
                                            const int* __restrict__ rowptr,
                                            const int* __restrict__ esrc,
                                            const float* __restrict__ enorm,
                                            const float* __restrict__ b1,
                                            float* __restrict__ h) {
    int node = blockIdx.x * 4 + (threadIdx.x >> 6);
    if (node >= N) return;
    int lane = threadIdx.x & 63;
    int beg = rowptr[node], end = rowptr[node + 1];
    float ax = 0.f, ay = 0.f;
    for (int j = beg; j < end; ++j) {
        int s = esrc[j];
        float w = enorm[j];
        float2 v = ((const float2*)(xw + (size_t)s * HD))[lane];
        ax = fmaf(w, v.x, ax);
        ay = fmaf(w, v.y, ay);
    }
    ax += b1[2 * lane];
    ay += b1[2 * lane + 1];
    float2 r = make_float2(fmaxf(ax, 0.f), fmaxf(ay, 0.f));
    ((float2*)(h + (size_t)node * HD))[lane] = r;
}

// ---------- GEMM2: xw2[N,47] = h[N,128] @ W2[128,47] ----------

__global__ __launch_bounds__(256) void gemm2(const float* __restrict__ h,
                                             const float* __restrict__ W2,
                                             float* __restrict__ xw2) {
    __shared__ float sH[64 * 130];     // padded stride 130 (33.3KB)
    __shared__ float sW[HD * 48];      // padded to 48 cols (24.6KB)
    int tx = threadIdx.x;
    size_t node0 = (size_t)blockIdx.x * 64;

    for (int i = tx; i < HD * 48; i += 256) {
        int k = i / 48, c = i - k * 48;
        sW[i] = (c < C) ? W2[k * C + c] : 0.f;
    }
    size_t base = node0 * HD;
    for (int i = tx; i < 64 * HD; i += 256) {
        size_t g = base + i;
        float v = (g < (size_t)N * HD) ? h[g] : 0.f;
        sH[(i >> 7) * 130 + (i & 127)] = v;
    }
    __syncthreads();

    int c0 = (tx & 15) * 3;        // 0..45
    int nb = (tx >> 4) * 4;        // 0..60
    float acc[4][3] = {};
    for (int k = 0; k < HD; ++k) {
        float w0 = sW[k * 48 + c0];
        float w1 = sW[k * 48 + c0 + 1];
        float w2 = sW[k * 48 + c0 + 2];
#pragma unroll
        for (int i = 0; i < 4; ++i) {
            float a = sH[(nb + i) * 130 + k];
            acc[i][0] = fmaf(a, w0, acc[i][0]);
            acc[i][1] = fmaf(a, w1, acc[i][1]);
            acc[i][2] = fmaf(a, w2, acc[i][2]);
        }
    }
#pragma unroll
    for (int i = 0; i < 4; ++i) {
        size_t node = node0 + nb + i;
        if (node < (size_t)N) {
#pragma unroll
            for (int j = 0; j < 3; ++j) {
                int c = c0 + j;
                if (c < C) xw2[node * C + c] = acc[i][j];
            }
        }
    }
}

// ---------- agg2: out[n] = b2 + sum_j norm_j * xw2[src_j] ----------

__global__ __launch_bounds__(256) void agg2(const float* __restrict__ xw2,
                                            const int* __restrict__ rowptr,
                                            const int* __restrict__ esrc,
                                            const float* __restrict__ enorm,
                                            const float* __restrict__ b2,
                                            float* __restrict__ out) {
    int node = blockIdx.x * 4 + (threadIdx.x >> 6);
    if (node >= N) return;
    int lane = threadIdx.x & 63;
    if (lane >= C) return;
    int beg = rowptr[node], end = rowptr[node + 1];
    float a = 0.f;
    for (int j = beg; j < end; ++j) {
        int s = esrc[j];
        float w = enorm[j];
        a = fmaf(w, xw2[(size_t)s * C + lane], a);
    }
    out[(size_t)node * C + lane] = a + b2[lane];
}

extern "C" void kernel_launch(void* const* d_in, const int* in_sizes, int n_in,
                              void* d_out, int out_size, void* d_ws, size_t ws_size,
                              hipStream_t stream) {
    const float* x  = (const float*)d_in[0];
    const int*   ei = (const int*)d_in[1];
    const float* W1 = (const float*)d_in[2];
    const float* b1 = (const float*)d_in[3];
    const float* W2 = (const float*)d_in[4];
    const float* b2 = (const float*)d_in[5];
    float* out = (float*)d_out;

    size_t off = 0;
    auto alloc = [&](size_t bytes) {
        void* p = (char*)d_ws + off;
        off += (bytes + 255) & ~(size_t)255;
        return p;
    };
    int*   cnt      = (int*)alloc((size_t)N * 4);
    int*   rowptr   = (int*)alloc((size_t)(N + 1) * 4);
    int*   fill     = (int*)alloc((size_t)N * 4);
    int*   partials = (int*)alloc(64 * 4);
    int*   pscan    = (int*)alloc(64 * 4);
    float* dinv     = (float*)alloc((size_t)N * 4);
    int*   esrc     = (int*)alloc((size_t)EN * 4);
    float* enorm    = (float*)alloc((size_t)EN * 4);
    float* xw       = (float*)alloc((size_t)N * HD * 4);
    float* h        = (float*)alloc((size_t)N * HD * 4);
    float* xw2      = (float*)alloc((size_t)N * C * 4);
    (void)ws_size;

    int gN  = (N + 255) / 256;
    int gE  = (E + 255) / 256;
    int gEN = (EN + 255) / 256;

    init_cnt<<<gN, 256, 0, stream>>>(cnt);
    count_deg<<<gE, 256, 0, stream>>>(ei + E, cnt);
    scan_pass1<<<NB_SCAN, 256, 0, stream>>>(cnt, partials);
    scan_pass2<<<1, 64, 0, stream>>>(partials, pscan, rowptr);
    scan_pass3<<<NB_SCAN, 256, 0, stream>>>(cnt, pscan, rowptr);
    dinv_fill<<<gN, 256, 0, stream>>>(cnt, dinv, fill);
    scatter_edges<<<gEN, 256, 0, stream>>>(ei, rowptr, fill, dinv, esrc, enorm);

    gemm1<<<(N + 63) / 64, 256, 0, stream>>>(x, W1, xw);
    agg1<<<(N + 3) / 4, 256, 0, stream>>>(xw, rowptr, esrc, enorm, b1, h);
    gemm2<<<(N + 63) / 64, 256, 0, stream>>>(h, W2, xw2);
    agg2<<<(N + 3) / 4, 256, 0, stream>>>(xw2, rowptr, esrc, enorm, b2, out);
}

// Round 2
// 492.799 us; speedup vs baseline: 1.5019x; 1.5019x over previous
//
#include <hip/hip_runtime.h>
#include <hip/hip_bf16.h>
#include <hip/hip_fp16.h>

// GCN 2-layer inference, N=100000, E=1600000, F_IN=100, H=128, C=47.
// R2: fp16 intermediates (xw, h, xw2) to halve gather bytes; packed int2
// edge records {src, norm}; 8-way unrolled gather loops for MLP (agg kernels
// were latency-serialized: VALUBusy 15%, HBM 33%); dinv/fill fused into
// scan_pass3; float4 staging loads in gemm1.

constexpr int N    = 100000;
constexpr int E    = 1600000;
constexpr int FIN  = 100;
constexpr int HD   = 128;
constexpr int C    = 47;
constexpr int C48  = 48;             // padded xw2 row
constexpr int EN   = E + N;          // edges + self loops
constexpr int SCAN_CHUNK = 2048;     // 256 threads * 8
constexpr int NB_SCAN = (N + SCAN_CHUNK - 1) / SCAN_CHUNK;  // 49

// ---------- CSR build ----------

__global__ void init_cnt(int* __restrict__ cnt) {
    int i = blockIdx.x * 256 + threadIdx.x;
    if (i < N) cnt[i] = 1;   // self loop
}

__global__ void count_deg(const int* __restrict__ dst, int* __restrict__ cnt) {
    int e = blockIdx.x * 256 + threadIdx.x;
    if (e < E) atomicAdd(&cnt[dst[e]], 1);
}

__global__ void scan_pass1(const int* __restrict__ cnt, int* __restrict__ partials) {
    int t = threadIdx.x, b = blockIdx.x;
    int base = b * SCAN_CHUNK + t * 8;
    int s = 0;
#pragma unroll
    for (int i = 0; i < 8; ++i) {
        int idx = base + i;
        if (idx < N) s += cnt[idx];
    }
    __shared__ int sm[256];
    sm[t] = s;
    __syncthreads();
    for (int off = 128; off > 0; off >>= 1) {
        if (t < off) sm[t] += sm[t + off];
        __syncthreads();
    }
    if (t == 0) partials[b] = sm[0];
}

__global__ void scan_pass2(const int* __restrict__ partials, int* __restrict__ pscan,
                           int* __restrict__ rowptr) {
    if (threadIdx.x == 0) {
        int run = 0;
        for (int i = 0; i < NB_SCAN; ++i) { pscan[i] = run; run += partials[i]; }
        rowptr[N] = run;   // == E + N
    }
}

// rowptr + dinv + fill-init in one pass
__global__ void scan_pass3(const int* __restrict__ cnt, const int* __restrict__ pscan,
                           int* __restrict__ rowptr, float* __restrict__ dinv,
                           int* __restrict__ fill) {
    int t = threadIdx.x, b = blockIdx.x;
    int base = b * SCAN_CHUNK + t * 8;
    int v[8];
    int s = 0;
#pragma unroll
    for (int i = 0; i < 8; ++i) {
        int idx = base + i;
        v[i] = (idx < N) ? cnt[idx] : 0;
        s += v[i];
    }
    __shared__ int sm[256];
    sm[t] = s;
    __syncthreads();
    for (int off = 1; off < 256; off <<= 1) {
        int tv = (t >= off) ? sm[t - off] : 0;
        __syncthreads();
        sm[t] += tv;
        __syncthreads();
    }
    int excl = sm[t] - s + pscan[b];
#pragma unroll
    for (int i = 0; i < 8; ++i) {
        int idx = base + i;
        if (idx < N) {
            rowptr[idx] = excl;
            excl += v[i];
            dinv[idx] = rsqrtf((float)v[i]);
            fill[idx] = 0;
        }
    }
}

__global__ void scatter_edges(const int* __restrict__ ei, const int* __restrict__ rowptr,
                              int* __restrict__ fill, const float* __restrict__ dinv,
                              int2* __restrict__ ep) {
    int e = blockIdx.x * 256 + threadIdx.x;
    if (e < E) {
        int s = ei[e];
        int d = ei[E + e];
        int pos = rowptr[d] + atomicAdd(&fill[d], 1);
        ep[pos] = make_int2(s, __float_as_int(dinv[s] * dinv[d]));
    } else if (e < EN) {
        int i = e - E;
        int pos = rowptr[i] + atomicAdd(&fill[i], 1);
        ep[pos] = make_int2(i, __float_as_int(dinv[i] * dinv[i]));
    }
}

// ---------- GEMM1: xw[N,128] (fp16) = x[N,100] @ W1[100,128] ----------

__global__ __launch_bounds__(256) void gemm1(const float* __restrict__ x,
                                             const float* __restrict__ W1,
                                             __half* __restrict__ xwh) {
    __shared__ float sW[FIN * HD];     // 12800 floats
    __shared__ float sX[64 * FIN];     // 6400 floats
    int tx = threadIdx.x;
    size_t node0 = (size_t)blockIdx.x * 64;

    // float4 staging
    const float4* W4 = (const float4*)W1;
    for (int i = tx; i < FIN * HD / 4; i += 256) ((float4*)sW)[i] = W4[i];
    size_t base4 = node0 * FIN / 4;          // node0*100 divisible by 4
    const float4* x4 = (const float4*)x;
    for (int i = tx; i < 64 * FIN / 4; i += 256) {
        size_t g = base4 + i;
        ((float4*)sX)[i] = (g < (size_t)N * FIN / 4) ? x4[g]
                                                     : make_float4(0.f, 0.f, 0.f, 0.f);
    }
    __syncthreads();

    int col = (tx & 31) * 4;        // 0..124
    int nb  = (tx >> 5) * 8;        // 0..56
    float4 acc[8];
#pragma unroll
    for (int i = 0; i < 8; ++i) acc[i] = make_float4(0.f, 0.f, 0.f, 0.f);

    for (int k = 0; k < FIN; ++k) {
        float4 b = *(const float4*)&sW[k * HD + col];
#pragma unroll
        for (int i = 0; i < 8; ++i) {
            float a = sX[(nb + i) * FIN + k];
            acc[i].x = fmaf(a, b.x, acc[i].x);
            acc[i].y = fmaf(a, b.y, acc[i].y);
            acc[i].z = fmaf(a, b.z, acc[i].z);
            acc[i].w = fmaf(a, b.w, acc[i].w);
        }
    }
#pragma unroll
    for (int i = 0; i < 8; ++i) {
        size_t node = node0 + nb + i;
        if (node < (size_t)N) {
            union { __half2 h2[2]; uint2 u; } p;
            p.h2[0] = __floats2half2_rn(acc[i].x, acc[i].y);
            p.h2[1] = __floats2half2_rn(acc[i].z, acc[i].w);
            *(uint2*)&xwh[node * HD + col] = p.u;
        }
    }
}

// ---------- agg1: h[n] (fp16) = relu(b1 + sum_j norm_j * xw[src_j]) ----------
// one wave per node, half2 per lane, 8-way unrolled gather for MLP

__global__ __launch_bounds__(256) void agg1(const __half2* __restrict__ xh2,
                                            const int* __restrict__ rowptr,
                                            const int2* __restrict__ ep,
                                            const float* __restrict__ b1,
                                            __half2* __restrict__ hh2) {
    int node = blockIdx.x * 4 + (threadIdx.x >> 6);
    if (node >= N) return;
    int lane = threadIdx.x & 63;
    int beg = rowptr[node], end = rowptr[node + 1];
    float ax = 0.f, ay = 0.f;
    int j = beg;
    for (; j + 8 <= end; j += 8) {
        int2 e0 = ep[j+0], e1 = ep[j+1], e2 = ep[j+2], e3 = ep[j+3];
        int2 e4 = ep[j+4], e5 = ep[j+5], e6 = ep[j+6], e7 = ep[j+7];
        __half2 v0 = xh2[(size_t)e0.x * 64 + lane];
        __half2 v1 = xh2[(size_t)e1.x * 64 + lane];
        __half2 v2 = xh2[(size_t)e2.x * 64 + lane];
        __half2 v3 = xh2[(size_t)e3.x * 64 + lane];
        __half2 v4 = xh2[(size_t)e4.x * 64 + lane];
        __half2 v5 = xh2[(size_t)e5.x * 64 + lane];
        __half2 v6 = xh2[(size_t)e6.x * 64 + lane];
        __half2 v7 = xh2[(size_t)e7.x * 64 + lane];
        float2 f;
        f = __half22float2(v0); ax = fmaf(__int_as_float(e0.y), f.x, ax); ay = fmaf(__int_as_float(e0.y), f.y, ay);
        f = __half22float2(v1); ax = fmaf(__int_as_float(e1.y), f.x, ax); ay = fmaf(__int_as_float(e1.y), f.y, ay);
        f = __half22float2(v2); ax = fmaf(__int_as_float(e2.y), f.x, ax); ay = fmaf(__int_as_float(e2.y), f.y, ay);
        f = __half22float2(v3); ax = fmaf(__int_as_float(e3.y), f.x, ax); ay = fmaf(__int_as_float(e3.y), f.y, ay);
        f = __half22float2(v4); ax = fmaf(__int_as_float(e4.y), f.x, ax); ay = fmaf(__int_as_float(e4.y), f.y, ay);
        f = __half22float2(v5); ax = fmaf(__int_as_float(e5.y), f.x, ax); ay = fmaf(__int_as_float(e5.y), f.y, ay);
        f = __half22float2(v6); ax = fmaf(__int_as_float(e6.y), f.x, ax); ay = fmaf(__int_as_float(e6.y), f.y, ay);
        f = __half22float2(v7); ax = fmaf(__int_as_float(e7.y), f.x, ax); ay = fmaf(__int_as_float(e7.y), f.y, ay);
    }
    for (; j < end; ++j) {
        int2 e = ep[j];
        float2 f = __half22float2(xh2[(size_t)e.x * 64 + lane]);
        float w = __int_as_float(e.y);
        ax = fmaf(w, f.x, ax);
        ay = fmaf(w, f.y, ay);
    }
    float2 bias = ((const float2*)b1)[lane];
    float rx = fmaxf(ax + bias.x, 0.f);
    float ry = fmaxf(ay + bias.y, 0.f);
    hh2[(size_t)node * 64 + lane] = __floats2half2_rn(rx, ry);
}

// ---------- GEMM2: xw2[N,48] (fp16, padded) = h[N,128] @ W2[128,47] ----------

__global__ __launch_bounds__(256) void gemm2(const __half2* __restrict__ hh2,
                                             const float* __restrict__ W2,
                                             __half* __restrict__ xw2h) {
    __shared__ float sH[64 * 130];     // padded stride 130
    __shared__ float sW[HD * 48];      // padded to 48 cols
    int tx = threadIdx.x;
    size_t node0 = (size_t)blockIdx.x * 64;

    for (int i = tx; i < HD * 48; i += 256) {
        int k = i / 48, c = i - k * 48;
        sW[i] = (c < C) ? W2[k * C + c] : 0.f;
    }
    size_t base2 = node0 * 64;
    for (int i = tx; i < 64 * 64; i += 256) {
        size_t g = base2 + i;
        float2 f = (g < (size_t)N * 64) ? __half22float2(hh2[g]) : make_float2(0.f, 0.f);
        int row = i >> 6, c2 = (i & 63) * 2;
        sH[row * 130 + c2]     = f.x;
        sH[row * 130 + c2 + 1] = f.y;
    }
    __syncthreads();

    int c0 = (tx & 15) * 3;        // 0..45
    int nb = (tx >> 4) * 4;        // 0..60
    float acc[4][3] = {};
    for (int k = 0; k < HD; ++k) {
        float w0 = sW[k * 48 + c0];
        float w1 = sW[k * 48 + c0 + 1];
        float w2 = sW[k * 48 + c0 + 2];
#pragma unroll
        for (int i = 0; i < 4; ++i) {
            float a = sH[(nb + i) * 130 + k];
            acc[i][0] = fmaf(a, w0, acc[i][0]);
            acc[i][1] = fmaf(a, w1, acc[i][1]);
            acc[i][2] = fmaf(a, w2, acc[i][2]);
        }
    }
#pragma unroll
    for (int i = 0; i < 4; ++i) {
        size_t node = node0 + nb + i;
        if (node < (size_t)N) {
#pragma unroll
            for (int jj = 0; jj < 3; ++jj) {
                int c = c0 + jj;
                if (c < C) xw2h[node * C48 + c] = __float2half_rn(acc[i][jj]);
            }
        }
    }
}

// ---------- agg2: out[n] = b2 + sum_j norm_j * xw2[src_j] ----------
// one wave per node; lanes 0..47 carry features (48..63 load pad, never store)

__global__ __launch_bounds__(256) void agg2(const __half* __restrict__ xw2h,
                                            const int* __restrict__ rowptr,
                                            const int2* __restrict__ ep,
                                            const float* __restrict__ b2,
                                            float* __restrict__ out) {
    int node = blockIdx.x * 4 + (threadIdx.x >> 6);
    if (node >= N) return;
    int lane = threadIdx.x & 63;
    int beg = rowptr[node], end = rowptr[node + 1];
    float a = 0.f;
    int j = beg;
    for (; j + 8 <= end; j += 8) {
        int2 e0 = ep[j+0], e1 = ep[j+1], e2 = ep[j+2], e3 = ep[j+3];
        int2 e4 = ep[j+4], e5 = ep[j+5], e6 = ep[j+6], e7 = ep[j+7];
        __half v0 = xw2h[(size_t)e0.x * C48 + lane];
        __half v1 = xw2h[(size_t)e1.x * C48 + lane];
        __half v2 = xw2h[(size_t)e2.x * C48 + lane];
        __half v3 = xw2h[(size_t)e3.x * C48 + lane];
        __half v4 = xw2h[(size_t)e4.x * C48 + lane];
        __half v5 = xw2h[(size_t)e5.x * C48 + lane];
        __half v6 = xw2h[(size_t)e6.x * C48 + lane];
        __half v7 = xw2h[(size_t)e7.x * C48 + lane];
        a = fmaf(__int_as_float(e0.y), __half2float(v0), a);
        a = fmaf(__int_as_float(e1.y), __half2float(v1), a);
        a = fmaf(__int_as_float(e2.y), __half2float(v2), a);
        a = fmaf(__int_as_float(e3.y), __half2float(v3), a);
        a = fmaf(__int_as_float(e4.y), __half2float(v4), a);
        a = fmaf(__int_as_float(e5.y), __half2float(v5), a);
        a = fmaf(__int_as_float(e6.y), __half2float(v6), a);
        a = fmaf(__int_as_float(e7.y), __half2float(v7), a);
    }
    for (; j < end; ++j) {
        int2 e = ep[j];
        a = fmaf(__int_as_float(e.y), __half2float(xw2h[(size_t)e.x * C48 + lane]), a);
    }
    if (lane < C) out[(size_t)node * C + lane] = a + b2[lane];
}

extern "C" void kernel_launch(void* const* d_in, const int* in_sizes, int n_in,
                              void* d_out, int out_size, void* d_ws, size_t ws_size,
                              hipStream_t stream) {
    const float* x  = (const float*)d_in[0];
    const int*   ei = (const int*)d_in[1];
    const float* W1 = (const float*)d_in[2];
    const float* b1 = (const float*)d_in[3];
    const float* W2 = (const float*)d_in[4];
    const float* b2 = (const float*)d_in[5];
    float* out = (float*)d_out;

    size_t off = 0;
    auto alloc = [&](size_t bytes) {
        void* p = (char*)d_ws + off;
        off += (bytes + 255) & ~(size_t)255;
        return p;
    };
    int*     cnt      = (int*)alloc((size_t)N * 4);
    int*     rowptr   = (int*)alloc((size_t)(N + 1) * 4);
    int*     fill     = (int*)alloc((size_t)N * 4);
    int*     partials = (int*)alloc(64 * 4);
    int*     pscan    = (int*)alloc(64 * 4);
    float*   dinv     = (float*)alloc((size_t)N * 4);
    int2*    ep       = (int2*)alloc((size_t)EN * 8);
    __half*  xwh      = (__half*)alloc((size_t)N * HD * 2);
    __half*  hh       = (__half*)alloc((size_t)N * HD * 2);
    __half*  xw2h     = (__half*)alloc((size_t)N * C48 * 2 + 64);  // +pad for lane>47 reads
    (void)ws_size;

    int gN  = (N + 255) / 256;
    int gE  = (E + 255) / 256;
    int gEN = (EN + 255) / 256;

    init_cnt<<<gN, 256, 0, stream>>>(cnt);
    count_deg<<<gE, 256, 0, stream>>>(ei + E, cnt);
    scan_pass1<<<NB_SCAN, 256, 0, stream>>>(cnt, partials);
    scan_pass2<<<1, 64, 0, stream>>>(partials, pscan, rowptr);
    scan_pass3<<<NB_SCAN, 256, 0, stream>>>(cnt, pscan, rowptr, dinv, fill);
    scatter_edges<<<gEN, 256, 0, stream>>>(ei, rowptr, fill, dinv, ep);

    gemm1<<<(N + 63) / 64, 256, 0, stream>>>(x, W1, xwh);
    agg1<<<(N + 3) / 4, 256, 0, stream>>>((const __half2*)xwh, rowptr, ep, b1, (__half2*)hh);
    gemm2<<<(N + 63) / 64, 256, 0, stream>>>((const __half2*)hh, W2, xw2h);
    agg2<<<(N + 3) / 4, 256, 0, stream>>>(xw2h, rowptr, ep, b2, out);
}

// Round 3
// 445.276 us; speedup vs baseline: 1.6621x; 1.1067x over previous
//
#include <hip/hip_runtime.h>
#include <hip/hip_bf16.h>
#include <hip/hip_fp16.h>

// GCN 2-layer inference, N=100000, E=1600000, F_IN=100, H=128, C=47.
// R3: (a) norm folded into GEMM outputs (rows pre-scaled by dinv[row]; agg
// multiplies the sum by dinv[node]) -> edge record is just `src` (4B), no
// enorm array, no dinv gathers in scatter. (b) atomic-free scatter: the
// counting pass records each edge's slot (epos), self-loop takes slot 0
// (written in scan_pass3), scatter does one random 4B write with no atomics.

constexpr int N    = 100000;
constexpr int E    = 1600000;
constexpr int FIN  = 100;
constexpr int HD   = 128;
constexpr int C    = 47;
constexpr int C48  = 48;             // padded xw2 row
constexpr int EN   = E + N;          // edges + self loops
constexpr int SCAN_CHUNK = 2048;     // 256 threads * 8
constexpr int NB_SCAN = (N + SCAN_CHUNK - 1) / SCAN_CHUNK;  // 49

// ---------- CSR build ----------

__global__ void init_cnt(int* __restrict__ cnt) {
    int i = blockIdx.x * 256 + threadIdx.x;
    if (i < N) cnt[i] = 1;   // self loop occupies slot 0 of every node
}

// count degrees AND record each edge's slot within its dst node (>=1)
__global__ void count_pos(const int* __restrict__ dst, int* __restrict__ cnt,
                          int* __restrict__ epos) {
    int e = blockIdx.x * 256 + threadIdx.x;
    if (e < E) epos[e] = atomicAdd(&cnt[dst[e]], 1);
}

__global__ void scan_pass1(const int* __restrict__ cnt, int* __restrict__ partials) {
    int t = threadIdx.x, b = blockIdx.x;
    int base = b * SCAN_CHUNK + t * 8;
    int s = 0;
#pragma unroll
    for (int i = 0; i < 8; ++i) {
        int idx = base + i;
        if (idx < N) s += cnt[idx];
    }
    __shared__ int sm[256];
    sm[t] = s;
    __syncthreads();
    for (int off = 128; off > 0; off >>= 1) {
        if (t < off) sm[t] += sm[t + off];
        __syncthreads();
    }
    if (t == 0) partials[b] = sm[0];
}

__global__ void scan_pass2(const int* __restrict__ partials, int* __restrict__ pscan,
                           int* __restrict__ rowptr) {
    if (threadIdx.x == 0) {
        int run = 0;
        for (int i = 0; i < NB_SCAN; ++i) { pscan[i] = run; run += partials[i]; }
        rowptr[N] = run;   // == E + N
    }
}

// rowptr + dinv + self-loop slot in one pass
__global__ void scan_pass3(const int* __restrict__ cnt, const int* __restrict__ pscan,
                           int* __restrict__ rowptr, float* __restrict__ dinv,
                           int* __restrict__ ep) {
    int t = threadIdx.x, b = blockIdx.x;
    int base = b * SCAN_CHUNK + t * 8;
    int v[8];
    int s = 0;
#pragma unroll
    for (int i = 0; i < 8; ++i) {
        int idx = base + i;
        v[i] = (idx < N) ? cnt[idx] : 0;
        s += v[i];
    }
    __shared__ int sm[256];
    sm[t] = s;
    __syncthreads();
    for (int off = 1; off < 256; off <<= 1) {
        int tv = (t >= off) ? sm[t - off] : 0;
        __syncthreads();
        sm[t] += tv;
        __syncthreads();
    }
    int excl = sm[t] - s + pscan[b];
#pragma unroll
    for (int i = 0; i < 8; ++i) {
        int idx = base + i;
        if (idx < N) {
            rowptr[idx] = excl;
            ep[excl] = idx;                  // self loop at slot 0
            dinv[idx] = rsqrtf((float)v[i]); // deg >= 1 always
            excl += v[i];
        }
    }
}

// atomic-free scatter: slot was precomputed in count_pos
__global__ void scatter_edges(const int* __restrict__ ei, const int* __restrict__ rowptr,
                              const int* __restrict__ epos, int* __restrict__ ep) {
    int e = blockIdx.x * 256 + threadIdx.x;
    if (e < E) {
        int s = ei[e];
        int d = ei[E + e];
        ep[rowptr[d] + epos[e]] = s;
    }
}

// ---------- GEMM1: xw[N,128] (fp16) = dinv[n] * (x[N,100] @ W1[100,128]) ----------

__global__ __launch_bounds__(256) void gemm1(const float* __restrict__ x,
                                             const float* __restrict__ W1,
                                             const float* __restrict__ dinv,
                                             __half* __restrict__ xwh) {
    __shared__ float sW[FIN * HD];     // 12800 floats
    __shared__ float sX[64 * FIN];     // 6400 floats
    int tx = threadIdx.x;
    size_t node0 = (size_t)blockIdx.x * 64;

    const float4* W4 = (const float4*)W1;
    for (int i = tx; i < FIN * HD / 4; i += 256) ((float4*)sW)[i] = W4[i];
    size_t base4 = node0 * FIN / 4;          // node0*100 divisible by 4
    const float4* x4 = (const float4*)x;
    for (int i = tx; i < 64 * FIN / 4; i += 256) {
        size_t g = base4 + i;
        ((float4*)sX)[i] = (g < (size_t)N * FIN / 4) ? x4[g]
                                                     : make_float4(0.f, 0.f, 0.f, 0.f);
    }
    __syncthreads();

    int col = (tx & 31) * 4;        // 0..124
    int nb  = (tx >> 5) * 8;        // 0..56
    float4 acc[8];
#pragma unroll
    for (int i = 0; i < 8; ++i) acc[i] = make_float4(0.f, 0.f, 0.f, 0.f);

    for (int k = 0; k < FIN; ++k) {
        float4 b = *(const float4*)&sW[k * HD + col];
#pragma unroll
        for (int i = 0; i < 8; ++i) {
            float a = sX[(nb + i) * FIN + k];
            acc[i].x = fmaf(a, b.x, acc[i].x);
            acc[i].y = fmaf(a, b.y, acc[i].y);
            acc[i].z = fmaf(a, b.z, acc[i].z);
            acc[i].w = fmaf(a, b.w, acc[i].w);
        }
    }
#pragma unroll
    for (int i = 0; i < 8; ++i) {
        size_t node = node0 + nb + i;
        if (node < (size_t)N) {
            float dv = dinv[node];
            union { __half2 h2[2]; uint2 u; } p;
            p.h2[0] = __floats2half2_rn(acc[i].x * dv, acc[i].y * dv);
            p.h2[1] = __floats2half2_rn(acc[i].z * dv, acc[i].w * dv);
            *(uint2*)&xwh[node * HD + col] = p.u;
        }
    }
}

// ---------- agg1: h[n] (fp16) = relu(b1 + dinv[n] * sum_j xw[src_j]) ----------

__global__ __launch_bounds__(256) void agg1(const __half2* __restrict__ xh2,
                                            const int* __restrict__ rowptr,
                                            const int* __restrict__ ep,
                                            const float* __restrict__ dinv,
                                            const float* __restrict__ b1,
                                            __half2* __restrict__ hh2) {
    int node = blockIdx.x * 4 + (threadIdx.x >> 6);
    if (node >= N) return;
    int lane = threadIdx.x & 63;
    int beg = rowptr[node], end = rowptr[node + 1];
    float ax = 0.f, ay = 0.f;
    int j = beg;
    for (; j + 8 <= end; j += 8) {
        int s0 = ep[j+0], s1 = ep[j+1], s2 = ep[j+2], s3 = ep[j+3];
        int s4 = ep[j+4], s5 = ep[j+5], s6 = ep[j+6], s7 = ep[j+7];
        __half2 v0 = xh2[(size_t)s0 * 64 + lane];
        __half2 v1 = xh2[(size_t)s1 * 64 + lane];
        __half2 v2 = xh2[(size_t)s2 * 64 + lane];
        __half2 v3 = xh2[(size_t)s3 * 64 + lane];
        __half2 v4 = xh2[(size_t)s4 * 64 + lane];
        __half2 v5 = xh2[(size_t)s5 * 64 + lane];
        __half2 v6 = xh2[(size_t)s6 * 64 + lane];
        __half2 v7 = xh2[(size_t)s7 * 64 + lane];
        float2 f;
        f = __half22float2(v0); ax += f.x; ay += f.y;
        f = __half22float2(v1); ax += f.x; ay += f.y;
        f = __half22float2(v2); ax += f.x; ay += f.y;
        f = __half22float2(v3); ax += f.x; ay += f.y;
        f = __half22float2(v4); ax += f.x; ay += f.y;
        f = __half22float2(v5); ax += f.x; ay += f.y;
        f = __half22float2(v6); ax += f.x; ay += f.y;
        f = __half22float2(v7); ax += f.x; ay += f.y;
    }
    for (; j < end; ++j) {
        float2 f = __half22float2(xh2[(size_t)ep[j] * 64 + lane]);
        ax += f.x; ay += f.y;
    }
    float dv = dinv[node];
    float2 bias = ((const float2*)b1)[lane];
    float rx = fmaxf(fmaf(dv, ax, bias.x), 0.f);
    float ry = fmaxf(fmaf(dv, ay, bias.y), 0.f);
    hh2[(size_t)node * 64 + lane] = __floats2half2_rn(rx, ry);
}

// ---------- GEMM2: xw2[N,48] (fp16, padded) = dinv[n] * (h[N,128] @ W2[128,47]) ----------

__global__ __launch_bounds__(256) void gemm2(const __half2* __restrict__ hh2,
                                             const float* __restrict__ W2,
                                             const float* __restrict__ dinv,
                                             __half* __restrict__ xw2h) {
    __shared__ float sH[64 * 130];     // padded stride 130
    __shared__ float sW[HD * 48];      // padded to 48 cols
    int tx = threadIdx.x;
    size_t node0 = (size_t)blockIdx.x * 64;

    for (int i = tx; i < HD * 48; i += 256) {
        int k = i / 48, c = i - k * 48;
        sW[i] = (c < C) ? W2[k * C + c] : 0.f;
    }
    size_t base2 = node0 * 64;
    for (int i = tx; i < 64 * 64; i += 256) {
        size_t g = base2 + i;
        float2 f = (g < (size_t)N * 64) ? __half22float2(hh2[g]) : make_float2(0.f, 0.f);
        int row = i >> 6, c2 = (i & 63) * 2;
        sH[row * 130 + c2]     = f.x;
        sH[row * 130 + c2 + 1] = f.y;
    }
    __syncthreads();

    int c0 = (tx & 15) * 3;        // 0..45
    int nb = (tx >> 4) * 4;        // 0..60
    float acc[4][3] = {};
    for (int k = 0; k < HD; ++k) {
        float w0 = sW[k * 48 + c0];
        float w1 = sW[k * 48 + c0 + 1];
        float w2 = sW[k * 48 + c0 + 2];
#pragma unroll
        for (int i = 0; i < 4; ++i) {
            float a = sH[(nb + i) * 130 + k];
            acc[i][0] = fmaf(a, w0, acc[i][0]);
            acc[i][1] = fmaf(a, w1, acc[i][1]);
            acc[i][2] = fmaf(a, w2, acc[i][2]);
        }
    }
#pragma unroll
    for (int i = 0; i < 4; ++i) {
        size_t node = node0 + nb + i;
        if (node < (size_t)N) {
            float dv = dinv[node];
#pragma unroll
            for (int jj = 0; jj < 3; ++jj) {
                int c = c0 + jj;
                if (c < C) xw2h[node * C48 + c] = __float2half_rn(acc[i][jj] * dv);
            }
        }
    }
}

// ---------- agg2: out[n] = b2 + dinv[n] * sum_j xw2[src_j] ----------

__global__ __launch_bounds__(256) void agg2(const __half* __restrict__ xw2h,
                                            const int* __restrict__ rowptr,
                                            const int* __restrict__ ep,
                                            const float* __restrict__ dinv,
                                            const float* __restrict__ b2,
                                            float* __restrict__ out) {
    int node = blockIdx.x * 4 + (threadIdx.x >> 6);
    if (node >= N) return;
    int lane = threadIdx.x & 63;
    int beg = rowptr[node], end = rowptr[node + 1];
    float a = 0.f;
    int j = beg;
    for (; j + 8 <= end; j += 8) {
        int s0 = ep[j+0], s1 = ep[j+1], s2 = ep[j+2], s3 = ep[j+3];
        int s4 = ep[j+4], s5 = ep[j+5], s6 = ep[j+6], s7 = ep[j+7];
        __half v0 = xw2h[(size_t)s0 * C48 + lane];
        __half v1 = xw2h[(size_t)s1 * C48 + lane];
        __half v2 = xw2h[(size_t)s2 * C48 + lane];
        __half v3 = xw2h[(size_t)s3 * C48 + lane];
        __half v4 = xw2h[(size_t)s4 * C48 + lane];
        __half v5 = xw2h[(size_t)s5 * C48 + lane];
        __half v6 = xw2h[(size_t)s6 * C48 + lane];
        __half v7 = xw2h[(size_t)s7 * C48 + lane];
        a += __half2float(v0) + __half2float(v1) + __half2float(v2) + __half2float(v3)
           + __half2float(v4) + __half2float(v5) + __half2float(v6) + __half2float(v7);
    }
    for (; j < end; ++j) {
        a += __half2float(xw2h[(size_t)ep[j] * C48 + lane]);
    }
    if (lane < C) out[(size_t)node * C + lane] = fmaf(dinv[node], a, b2[lane]);
}

extern "C" void kernel_launch(void* const* d_in, const int* in_sizes, int n_in,
                              void* d_out, int out_size, void* d_ws, size_t ws_size,
                              hipStream_t stream) {
    const float* x  = (const float*)d_in[0];
    const int*   ei = (const int*)d_in[1];
    const float* W1 = (const float*)d_in[2];
    const float* b1 = (const float*)d_in[3];
    const float* W2 = (const float*)d_in[4];
    const float* b2 = (const float*)d_in[5];
    float* out = (float*)d_out;

    size_t off = 0;
    auto alloc = [&](size_t bytes) {
        void* p = (char*)d_ws + off;
        off += (bytes + 255) & ~(size_t)255;
        return p;
    };
    int*     cnt      = (int*)alloc((size_t)N * 4);
    int*     rowptr   = (int*)alloc((size_t)(N + 1) * 4);
    int*     epos     = (int*)alloc((size_t)E * 4);
    int*     partials = (int*)alloc(64 * 4);
    int*     pscan    = (int*)alloc(64 * 4);
    float*   dinv     = (float*)alloc((size_t)N * 4);
    int*     ep       = (int*)alloc((size_t)EN * 4);
    __half*  xwh      = (__half*)alloc((size_t)N * HD * 2);
    __half*  hh       = (__half*)alloc((size_t)N * HD * 2);
    __half*  xw2h     = (__half*)alloc((size_t)N * C48 * 2 + 64);  // +pad for lane>47 reads
    (void)ws_size;

    int gN = (N + 255) / 256;
    int gE = (E + 255) / 256;

    init_cnt<<<gN, 256, 0, stream>>>(cnt);
    count_pos<<<gE, 256, 0, stream>>>(ei + E, cnt, epos);
    scan_pass1<<<NB_SCAN, 256, 0, stream>>>(cnt, partials);
    scan_pass2<<<1, 64, 0, stream>>>(partials, pscan, rowptr);
    scan_pass3<<<NB_SCAN, 256, 0, stream>>>(cnt, pscan, rowptr, dinv, ep);
    scatter_edges<<<gE, 256, 0, stream>>>(ei, rowptr, epos, ep);

    gemm1<<<(N + 63) / 64, 256, 0, stream>>>(x, W1, dinv, xwh);
    agg1<<<(N + 3) / 4, 256, 0, stream>>>((const __half2*)xwh, rowptr, ep, dinv, b1, (__half2*)hh);
    gemm2<<<(N + 63) / 64, 256, 0, stream>>>((const __half2*)hh, W2, dinv, xw2h);
    agg2<<<(N + 3) / 4, 256, 0, stream>>>(xw2h, rowptr, ep, dinv, b2, out);
}